// Round 1
// baseline (74.561 us; speedup 1.0000x reference)
//
#include <hip/hip_runtime.h>
#include <math.h>

#define LOG2E 1.4426950408889634f
#define LN2   0.6931471805599453f

static constexpr int M = 1024;
static constexpr int N = 65536;

typedef float v2f __attribute__((ext_vector_type(2)));

// packed f32 fma: d = a*b + c on both lanes (gfx90a+/gfx950 VOP3P)
__device__ inline v2f pk_fma(v2f a, v2f b, v2f c) {
    v2f d;
    asm("v_pk_fma_f32 %0, %1, %2, %3" : "=v"(d) : "v"(a), "v"(b), "v"(c));
    return d;
}

__device__ inline float wave_max64(float v) {
    #pragma unroll
    for (int o = 32; o > 0; o >>= 1) v = fmaxf(v, __shfl_xor(v, o));
    return v;
}
__device__ inline float wave_sum64(float v) {
    #pragma unroll
    for (int o = 32; o > 0; o >>= 1) v += __shfl_xor(v, o);
    return v;
}

// ---------------- prep: one block, 1024 threads ----------------
// Writes pair-interleaved coefficient table to ws[0 .. M*6):
//   component j -> pair p=j>>1, sub=j&1; coef c at ws[p*12 + 2*c + sub]
// ws[M*6] = maxt2 - lse2 (the only scalar the main kernel needs).
__global__ __launch_bounds__(1024)
void gm_prep(const float* __restrict__ mu,
             const float* __restrict__ A,
             const float* __restrict__ w,
             float* __restrict__ ws) {
    __shared__ float redA[16];
    __shared__ float redB[16];
    const int t    = threadIdx.x;
    const int lane = t & 63;
    const int wv   = t >> 6;

    const float4 a = ((const float4*)A)[t];       // A00,A01,A10,A11
    const float g00 = a.x*a.x + a.y*a.y;
    const float g01 = a.x*a.z + a.y*a.w;
    const float g11 = a.z*a.z + a.w*a.w;
    const float2 m  = ((const float2*)mu)[t];
    const float gm0 = g00*m.x + g01*m.y;
    const float gm1 = g01*m.x + g11*m.y;
    const float mGm = gm0*m.x + gm1*m.y;
    const float det = g00*g11 - g01*g01;

    const float w2 = w[t] * LOG2E;                           // log2-domain w
    const float t2 = w2 + 0.5f * __builtin_amdgcn_logf(det); // + 0.5*log2(det)

    float mw = wave_max64(w2);
    float mt = wave_max64(t2);
    if (lane == 0) { redA[wv] = mw; redB[wv] = mt; }
    __syncthreads();
    float wmax2 = redA[0], maxt2 = redB[0];
    #pragma unroll
    for (int i = 1; i < 16; i++) {
        wmax2 = fmaxf(wmax2, redA[i]);
        maxt2 = fmaxf(maxt2, redB[i]);
    }
    __syncthreads();                 // protect redA before reuse
    const float sw = wave_sum64(__builtin_amdgcn_exp2f(w2 - wmax2));
    if (lane == 0) redA[wv] = sw;

    // pair-interleaved store for packed main-loop reads
    float* c = ws + (t >> 1)*12 + (t & 1);
    c[0]  = t2 - maxt2 - LOG2E * mGm;   // c0
    c[2]  = LOG2E * 2.0f * gm0;         // c1 * x
    c[4]  = LOG2E * 2.0f * gm1;         // c2 * y
    c[6]  = -LOG2E * g00;               // c3 * xx
    c[8]  = -LOG2E * 2.0f * g01;        // c4 * xy
    c[10] = -LOG2E * g11;               // c5 * yy

    __syncthreads();
    if (t == 0) {
        float se = 0.0f;
        #pragma unroll
        for (int i = 0; i < 16; i++) se += redA[i];
        ws[M*6] = maxt2 - (wmax2 + __builtin_amdgcn_logf(se));
    }
}

// ---------------- main: 512 blocks x 1024 threads ----------------
// Block handles 128 samples (lane ln: base+ln and base+64+ln).
// Wave wv owns components [wv*64, wv*64+64) = 32 pairs.
// 2 blocks/CU -> 32 waves/CU (8/SIMD); launch_bounds caps VGPR at 64.
__global__ __launch_bounds__(1024, 8)
void gm_main(const float* __restrict__ sample,
             const float* __restrict__ ws,
             float* __restrict__ out) {
    __shared__ __align__(16) float coef[M*6];     // 24 KiB pair-interleaved
    __shared__ float partial[16*128];             // 8 KiB

    const int t    = threadIdx.x;
    const int lane = t & 63;
    const int wv   = t >> 6;                      // 0..15
    const int base = blockIdx.x * 128;

    // sample loads issued first (overlap with coef staging)
    const float2 p0 = ((const float2*)sample)[base + lane];
    const float2 p1 = ((const float2*)sample)[base + 64 + lane];

    const float k_off = ws[M*6];                  // maxt2 - lse2 (uniform)

    // coef table -> LDS: 3072 float2, 3 per thread, coalesced
    {
        const float2* src = (const float2*)ws;
        float2* dst = (float2*)coef;
        #pragma unroll
        for (int i = 0; i < 3; i++) dst[t + 1024*i] = src[t + 1024*i];
    }
    __syncthreads();

    // broadcast pairs per sample
    const v2f X0  = {p0.x, p0.x},      Y0  = {p0.y, p0.y};
    const v2f XX0 = {p0.x*p0.x, p0.x*p0.x};
    const v2f XY0 = {p0.x*p0.y, p0.x*p0.y};
    const v2f YY0 = {p0.y*p0.y, p0.y*p0.y};
    const v2f X1  = {p1.x, p1.x},      Y1  = {p1.y, p1.y};
    const v2f XX1 = {p1.x*p1.x, p1.x*p1.x};
    const v2f XY1 = {p1.x*p1.y, p1.x*p1.y};
    const v2f YY1 = {p1.y*p1.y, p1.y*p1.y};

    float acc0a = 0.0f, acc0b = 0.0f, acc1a = 0.0f, acc1b = 0.0f;

    const float4* cw = (const float4*)coef + wv*32*3;   // wave's 32 pairs
    #pragma unroll 4
    for (int jj = 0; jj < 32; jj++) {
        const float4 q0 = cw[jj*3 + 0];   // c0a c0b c1a c1b
        const float4 q1 = cw[jj*3 + 1];   // c2a c2b c3a c3b
        const float4 q2 = cw[jj*3 + 2];   // c4a c4b c5a c5b
        const v2f c0 = {q0.x, q0.y}, c1 = {q0.z, q0.w};
        const v2f c2 = {q1.x, q1.y}, c3 = {q1.z, q1.w};
        const v2f c4 = {q2.x, q2.y}, c5 = {q2.z, q2.w};

        v2f v0 = pk_fma(c5, YY0, pk_fma(c4, XY0, pk_fma(c3, XX0,
                 pk_fma(c2, Y0,  pk_fma(c1, X0, c0)))));
        v2f v1 = pk_fma(c5, YY1, pk_fma(c4, XY1, pk_fma(c3, XX1,
                 pk_fma(c2, Y1,  pk_fma(c1, X1, c0)))));

        acc0a += __builtin_amdgcn_exp2f(v0.x);
        acc0b += __builtin_amdgcn_exp2f(v0.y);
        acc1a += __builtin_amdgcn_exp2f(v1.x);
        acc1b += __builtin_amdgcn_exp2f(v1.y);
    }

    partial[wv*128 + lane]      = acc0a + acc0b;
    partial[wv*128 + 64 + lane] = acc1a + acc1b;
    __syncthreads();

    if (t < 128) {
        float s = partial[t];
        #pragma unroll
        for (int i = 1; i < 16; i++) s += partial[i*128 + t];
        out[base + t] = LN2 * (k_off + __builtin_amdgcn_logf(s));
    }
}

extern "C" void kernel_launch(void* const* d_in, const int* in_sizes, int n_in,
                              void* d_out, int out_size, void* d_ws, size_t ws_size,
                              hipStream_t stream) {
    const float* sample = (const float*)d_in[0];
    const float* mu     = (const float*)d_in[1];
    const float* A      = (const float*)d_in[2];
    const float* w      = (const float*)d_in[3];
    (void)in_sizes; (void)n_in; (void)out_size; (void)ws_size;

    gm_prep<<<1, 1024, 0, stream>>>(mu, A, w, (float*)d_ws);
    gm_main<<<N/128, 1024, 0, stream>>>(sample, (const float*)d_ws, (float*)d_out);
}